// Round 9
// baseline (13827.084 us; speedup 1.0000x reference)
//
#include <hip/hip_runtime.h>

#define T_DIM 1024
#define B_DIM 128
#define I_DIM 512
#define H_DIM 1024
#define O_DIM 512
#define TC 64
#define NCHUNK (T_DIM / TC)

typedef _Float16 half8 __attribute__((ext_vector_type(8)));
typedef _Float16 half4v __attribute__((ext_vector_type(4)));
typedef float floatx4 __attribute__((ext_vector_type(4)));
typedef unsigned int uint4v __attribute__((ext_vector_type(4)));

__device__ __forceinline__ void gload_lds16(const void* g, void* l) {
  __builtin_amdgcn_global_load_lds(
      (const __attribute__((address_space(1))) void*)g,
      (__attribute__((address_space(3))) void*)l, 16, 0, 0);
}

__device__ __forceinline__ float sigmoidf_(float x) {
  return 1.f / (1.f + __expf(-x));
}
__device__ __forceinline__ float tanhf_(float x) {
  float e = __expf(fminf(-2.f * x, 60.f));
  return (1.f - e) / (1.f + e);
}

// ---------------- prep kernels ----------------
__global__ __launch_bounds__(256) void k_cvt(const float* __restrict__ s,
                                             _Float16* __restrict__ d, int n4) {
  int i = blockIdx.x * 256 + threadIdx.x;
  if (i < n4) {
    float4 v = ((const float4*)s)[i];
    half4v h = {(_Float16)v.x, (_Float16)v.y, (_Float16)v.z, (_Float16)v.w};
    ((half4v*)d)[i] = h;
  }
}

__global__ __launch_bounds__(256) void build_bcat(const float* __restrict__ a,
                                                  const float* __restrict__ b,
                                                  const float* __restrict__ c,
                                                  const float* __restrict__ d,
                                                  float* __restrict__ o) {
  int i = blockIdx.x * 256 + threadIdx.x;
  if (i < 4096) {
    const float* p = (i < 1024) ? a : (i < 2048) ? b : (i < 3072) ? c : d;
    o[i] = p[i & 1023];
  }
}

// ---------------- device tile: input GEMM (A = fp32 x, direct) ----------------
// C[row=tl*128+b][gcol] ; gcol<3072 -> rz_dst[row][3072], else skip_dst[row][1024]
__device__ __forceinline__ void gemm_in_tile(
    const float* __restrict__ x, const _Float16* __restrict__ Wcat,
    const float* __restrict__ bias, _Float16* __restrict__ rz_dst,
    _Float16* __restrict__ skip_dst, int t0, int bx, int by, int tid,
    _Float16* As, _Float16* Bs) {
  const bool act = tid < 256;
  const int lane = tid & 63, wv = tid >> 6;
  const int wm = (wv >> 1) & 1, wn = wv & 1;
  const int lj = lane & 15, lk = lane >> 4;
  const size_t rowA0 = (size_t)by * 128, colB0 = (size_t)bx * 128;
  floatx4 acc[4][4] = {};
  for (int kb = 0; kb < I_DIM; kb += 64) {
    __syncthreads();
    if (act) {
      float4 av[8];
#pragma unroll
      for (int i = 0; i < 8; ++i) {
        int u = i * 256 + tid;
        int r = u >> 4, f4 = u & 15;
        size_t grow = rowA0 + r;
        size_t b = grow & 127, tl = grow >> 7;
        av[i] = *(const float4*)(x + (b * T_DIM + t0 + tl) * I_DIM + kb + f4 * 4);
      }
#pragma unroll
      for (int i = 0; i < 4; ++i) {
        int q = i * 256 + tid;
        int r = q >> 3, cc = q & 7;
        gload_lds16(Wcat + (colB0 + r) * (size_t)I_DIM + kb + cc * 8,
                    Bs + (size_t)(i * 4 + wv) * 512);
      }
#pragma unroll
      for (int i = 0; i < 8; ++i) {
        int u = i * 256 + tid;
        int r = u >> 4, f4 = u & 15;
        half4v h = {(_Float16)av[i].x, (_Float16)av[i].y, (_Float16)av[i].z,
                    (_Float16)av[i].w};
        *(half4v*)(As + r * 64 + f4 * 4) = h;
      }
    }
    __syncthreads();
    if (act) {
#pragma unroll
      for (int ks = 0; ks < 2; ++ks) {
        half8 af[4], bf[4];
#pragma unroll
        for (int am = 0; am < 4; ++am)
          af[am] = *(const half8*)(As + (wm * 64 + am * 16 + lj) * 64 + ks * 32 + lk * 8);
#pragma unroll
        for (int bn = 0; bn < 4; ++bn)
          bf[bn] = *(const half8*)(Bs + (wn * 64 + bn * 16 + lj) * 64 + ks * 32 + lk * 8);
#pragma unroll
        for (int am = 0; am < 4; ++am)
#pragma unroll
          for (int bn = 0; bn < 4; ++bn)
            acc[am][bn] =
                __builtin_amdgcn_mfma_f32_16x16x32_f16(af[am], bf[bn], acc[am][bn], 0, 0, 0);
      }
    }
  }
  if (act) {
#pragma unroll
    for (int am = 0; am < 4; ++am)
#pragma unroll
      for (int bn = 0; bn < 4; ++bn)
#pragma unroll
        for (int rr = 0; rr < 4; ++rr) {
          size_t grow = rowA0 + wm * 64 + am * 16 + lk * 4 + rr;
          int gcol = (int)colB0 + wn * 64 + bn * 16 + lj;
          float v = acc[am][bn][rr] + bias[gcol];
          if (gcol < 3072) rz_dst[grow * 3072 + gcol] = (_Float16)v;
          else skip_dst[grow * 1024 + (gcol - 3072)] = (_Float16)v;
        }
  }
}

// ---------------- device tile: output GEMM ----------------
__device__ __forceinline__ void gemm_out_tile(
    const _Float16* __restrict__ A, const _Float16* __restrict__ Bw,
    const float* __restrict__ bias, float* __restrict__ C32, int t0, int bx,
    int by, int tid, _Float16* As, _Float16* Bs) {
  const bool act = tid < 256;
  const int lane = tid & 63, wv = tid >> 6;
  const int wm = (wv >> 1) & 1, wn = wv & 1;
  const int lj = lane & 15, lk = lane >> 4;
  const size_t rowA0 = (size_t)by * 128, colB0 = (size_t)bx * 128;
  floatx4 acc[4][4] = {};
  for (int kb = 0; kb < H_DIM; kb += 64) {
    __syncthreads();
    if (act) {
#pragma unroll
      for (int i = 0; i < 4; ++i) {
        int q = i * 256 + tid;
        int r = q >> 3, cc = q & 7;
        gload_lds16(A + (rowA0 + r) * (size_t)H_DIM + kb + cc * 8,
                    As + (size_t)(i * 4 + wv) * 512);
      }
#pragma unroll
      for (int i = 0; i < 4; ++i) {
        int q = i * 256 + tid;
        int r = q >> 3, cc = q & 7;
        gload_lds16(Bw + (colB0 + r) * (size_t)H_DIM + kb + cc * 8,
                    Bs + (size_t)(i * 4 + wv) * 512);
      }
    }
    __syncthreads();
    if (act) {
#pragma unroll
      for (int ks = 0; ks < 2; ++ks) {
        half8 af[4], bf[4];
#pragma unroll
        for (int am = 0; am < 4; ++am)
          af[am] = *(const half8*)(As + (wm * 64 + am * 16 + lj) * 64 + ks * 32 + lk * 8);
#pragma unroll
        for (int bn = 0; bn < 4; ++bn)
          bf[bn] = *(const half8*)(Bs + (wn * 64 + bn * 16 + lj) * 64 + ks * 32 + lk * 8);
#pragma unroll
        for (int am = 0; am < 4; ++am)
#pragma unroll
          for (int bn = 0; bn < 4; ++bn)
            acc[am][bn] =
                __builtin_amdgcn_mfma_f32_16x16x32_f16(af[am], bf[bn], acc[am][bn], 0, 0, 0);
      }
    }
  }
  if (act) {
#pragma unroll
    for (int am = 0; am < 4; ++am)
#pragma unroll
      for (int bn = 0; bn < 4; ++bn)
#pragma unroll
        for (int rr = 0; rr < 4; ++rr) {
          size_t grow = rowA0 + wm * 64 + am * 16 + lk * 4 + rr;
          size_t gcol = colB0 + wn * 64 + bn * 16 + lj;
          size_t tl = grow >> 7, b = grow & 127;
          C32[b * (size_t)(T_DIM * O_DIM) + (t0 + tl) * (size_t)O_DIM + gcol] =
              acc[am][bn][rr] + bias[gcol];
        }
  }
}

// ---------------- device: one LayerNorm row (hs already includes skip) ----------------
__device__ __forceinline__ void ln_one_row(int row, const _Float16* __restrict__ hs,
                                           const float* __restrict__ gamma,
                                           const float* __restrict__ beta,
                                           _Float16* __restrict__ outp, int tid,
                                           float* ps) {
  const bool act = tid < 256;
  const int lane = tid & 63, wv = tid >> 6;
  float v[4];
  float s = 0.f, s2 = 0.f;
  if (act) {
    half4v hv = *(const half4v*)(hs + (size_t)row * 1024 + tid * 4);
#pragma unroll
    for (int j = 0; j < 4; ++j) {
      v[j] = (float)hv[j];
      s += v[j];
      s2 += v[j] * v[j];
    }
#pragma unroll
    for (int o = 32; o > 0; o >>= 1) {
      s += __shfl_xor(s, o, 64);
      s2 += __shfl_xor(s2, o, 64);
    }
    if (lane == 0) { ps[wv * 2] = s; ps[wv * 2 + 1] = s2; }
  }
  __syncthreads();
  if (act) {
    s = ps[0] + ps[2] + ps[4] + ps[6];
    s2 = ps[1] + ps[3] + ps[5] + ps[7];
    const float mu = s * (1.f / 1024.f);
    const float var = s2 * (1.f / 1024.f) - mu * mu;
    const float rstd = rsqrtf(var + 1e-5f);
    half4v ov;
#pragma unroll
    for (int j = 0; j < 4; ++j)
      ov[j] = (_Float16)((v[j] - mu) * rstd * gamma[tid * 4 + j] + beta[tid * 4 + j]);
    *(half4v*)(outp + (size_t)row * 1024 + tid * 4) = ov;
  }
  __syncthreads();
}

// ---------------- standalone wrappers ----------------
__global__ __launch_bounds__(256) void gemm_in_k(
    const float* __restrict__ x, const _Float16* __restrict__ Wcat,
    const float* __restrict__ bcat, _Float16* __restrict__ rz,
    _Float16* __restrict__ skip, int t0) {
  __shared__ __align__(16) char sm[32768];
  gemm_in_tile(x, Wcat, bcat, rz, skip, t0, blockIdx.x, blockIdx.y, threadIdx.x,
               (_Float16*)sm, (_Float16*)(sm + 16384));
}

__global__ __launch_bounds__(256) void gemm_out_k(
    const _Float16* __restrict__ A, const _Float16* __restrict__ Bw,
    const float* __restrict__ bias, float* __restrict__ C32, int t0) {
  __shared__ __align__(16) char sm[32768];
  gemm_out_tile(A, Bw, bias, C32, t0, blockIdx.x, blockIdx.y, threadIdx.x,
                (_Float16*)sm, (_Float16*)(sm + 16384));
}

__global__ __launch_bounds__(256) void ln_k(const _Float16* __restrict__ hs,
                                            const float* __restrict__ gamma,
                                            const float* __restrict__ beta,
                                            _Float16* __restrict__ normed) {
  __shared__ float ps[8];
  ln_one_row(blockIdx.x, hs, gamma, beta, normed, threadIdx.x, ps);
}

// ---------------- fused: scan (blocks 0-255) + pipeline workers (256-511) ----------------
// Scan = R3 protocol verbatim (proven 238us): stagers waves0-3, publisher
// wave0 (coalesced from hout LDS, sc0 sc1 fabric-coherent), poll wave5,
// barriers A,B,C,D, bg=bid&7. z-wave also writes hs16 = h + skip (plain
// cached stores, consumed next launch). Workers are fully independent of the
// scan within a launch (different chunks/buffers) -> no deadlock possible.
__global__ __launch_bounds__(384, 3) void fused_k(
    const _Float16* __restrict__ rznx_s,  // [TC][128][3072] chunk c
    const _Float16* __restrict__ skip_s,  // [TC][128][1024] chunk c
    const _Float16* __restrict__ Whcat,
    const float* __restrict__ bhr, const float* __restrict__ bhz,
    const float* __restrict__ bhn,
    _Float16* __restrict__ h16, float* __restrict__ h32,
    _Float16* __restrict__ hs16_s,  // [TC][128][1024] chunk c (h+skip)
    int* __restrict__ flags, int chunk,
    // worker: input gemm for chunk c+1
    const float* __restrict__ x, const _Float16* __restrict__ Wcat,
    const float* __restrict__ bcat, _Float16* __restrict__ rznx_n,
    _Float16* __restrict__ skip_n, int do_gin, int t0_gin,
    // worker: LN for chunk c-1
    const _Float16* __restrict__ hs16_p, const float* __restrict__ gamma,
    const float* __restrict__ beta, _Float16* __restrict__ normed_p, int do_ln,
    // worker: output gemm for chunk c-2
    const _Float16* __restrict__ normed_pp, const _Float16* __restrict__ Wout16,
    const float* __restrict__ bout, float* __restrict__ outp, int do_gout,
    int t0_gout) {
  __shared__ __align__(16) char smem[38400];
  const int tid = threadIdx.x;

  if (blockIdx.x < 256) {
    // ================= scan role =================
    _Float16* hlds = (_Float16*)smem;             // 32768 B
    float* exch = (float*)(smem + 32768);         // [2][2][272] = 4352 B
    _Float16* hout = (_Float16*)(smem + 37376);   // [16][32] = 1024 B
    const int lane = tid & 63, wv = tid >> 6;
    const int g = wv % 3, jh = wv / 3;
    const int bg = blockIdx.x & 7, js = blockIdx.x >> 3;
    const int b0 = bg * 16;
    const int jbase = js * 32 + jh * 16;
    const int lj = lane & 15, lk = lane >> 4;
    const int jcol = jbase + lj;

    half8 wf[32];
    {
      const _Float16* wb = Whcat + ((size_t)g * 1024 + jcol) * 1024 + lk * 8;
#pragma unroll
      for (int ks = 0; ks < 32; ++ks) wf[ks] = *(const half8*)(wb + ks * 32);
    }
    const float* bh = (g == 0) ? bhr : (g == 1) ? bhz : bhn;
    const float biasg = bh[jcol];
    float hown[4];
    if (g == 1) {
#pragma unroll
      for (int r = 0; r < 4; ++r)
        hown[r] = h32[(size_t)(b0 + lk * 4 + r) * 1024 + jcol];
    }
    int cur = 0;
    for (int t = 0; t < TC; ++t) {
      const int gs = chunk * TC + t;
      // prefetch x-side gate inputs (independent of h)
      const _Float16* xg = rznx_s + ((size_t)t * 128 + b0) * 3072 + g * 1024 + jcol;
      float xv[4];
#pragma unroll
      for (int r = 0; r < 4; ++r) xv[r] = (float)xg[(size_t)(lk * 4 + r) * 3072];
      float nxv[4], skv[4];
      if (g == 1) {
#pragma unroll
        for (int r = 0; r < 4; ++r) {
          nxv[r] = (float)rznx_s[((size_t)t * 128 + b0 + lk * 4 + r) * 3072 + 2048 + jcol];
          skv[r] = (float)skip_s[((size_t)t * 128 + b0 + lk * 4 + r) * 1024 + jcol];
        }
      }
      // stage h16[cur] -> swizzled LDS (fabric-coherent loads)
      if (tid < 256) {
        const _Float16* hsrc = h16 + (size_t)cur * (128 * 1024) + (size_t)b0 * 1024;
        uint4v vv[8];
        const char* ap[8];
#pragma unroll
        for (int i = 0; i < 8; ++i) {
          int q = tid + i * 256;
          int b = q >> 7, c = q & 127;
          ap[i] = (const char*)(hsrc + b * 1024 + c * 8);
        }
#pragma unroll
        for (int i = 0; i < 8; ++i)
          asm volatile("global_load_dwordx4 %0, %1, off sc0 sc1"
                       : "=v"(vv[i]) : "v"(ap[i]));
        asm volatile("s_waitcnt vmcnt(0)" ::: "memory");
#pragma unroll
        for (int i = 0; i < 8; ++i) {
          int q = tid + i * 256;
          int b = q >> 7, c = q & 127;
          *(uint4v*)((char*)hlds + b * 2048 + ((c ^ (b & 7)) * 16)) = vv[i];
        }
      }
      __syncthreads();  // (A)
      floatx4 acc = {0.f, 0.f, 0.f, 0.f};
#pragma unroll
      for (int ks = 0; ks < 32; ++ks) {
        int c = ks * 4 + lk;
        int b = lj;
        half8 af = *(const half8*)((const char*)hlds + b * 2048 + ((c ^ (b & 7)) * 16));
        acc = __builtin_amdgcn_mfma_f32_16x16x32_f16(af, wf[ks], acc, 0, 0, 0);
      }
      float zv[4] = {0.f, 0.f, 0.f, 0.f};
      if (g == 0) {
#pragma unroll
        for (int r = 0; r < 4; ++r)
          exch[(jh * 2 + 0) * 272 + (lk * 4 + r) * 17 + lj] =
              sigmoidf_(acc[r] + biasg + xv[r]);
      } else if (g == 2) {
#pragma unroll
        for (int r = 0; r < 4; ++r)
          exch[(jh * 2 + 1) * 272 + (lk * 4 + r) * 17 + lj] = acc[r] + biasg;
      } else {
#pragma unroll
        for (int r = 0; r < 4; ++r) zv[r] = sigmoidf_(acc[r] + biasg + xv[r]);
      }
      __syncthreads();  // (B)
      if (g == 1) {
#pragma unroll
        for (int r = 0; r < 4; ++r) {
          float rr = exch[(jh * 2 + 0) * 272 + (lk * 4 + r) * 17 + lj];
          float np = exch[(jh * 2 + 1) * 272 + (lk * 4 + r) * 17 + lj];
          float n = tanhf_(nxv[r] + rr * np);
          float hn = (1.f - zv[r]) * n + zv[r] * hown[r];
          hown[r] = hn;
          hout[(lk * 4 + r) * 32 + jh * 16 + lj] = (_Float16)hn;
          // hs16 = h + skip (plain cached, consumed next launch)
          hs16_s[((size_t)t * 128 + b0 + lk * 4 + r) * 1024 + jcol] =
              (_Float16)(hn + skv[r]);
        }
      }
      __syncthreads();  // (C)
      if (wv == 0) {
        int row = lane >> 2, c = lane & 3;
        uint4v hv = *(const uint4v*)((const char*)hout + row * 64 + c * 16);
        char* p1 = (char*)(h16 + (size_t)(cur ^ 1) * (128 * 1024) +
                           (size_t)(b0 + row) * 1024 + js * 32 + c * 8);
        asm volatile("global_store_dwordx4 %0, %1, off sc0 sc1"
                     :: "v"(p1), "v"(hv) : "memory");
        asm volatile("s_waitcnt vmcnt(0)" ::: "memory");
        if (lane == 0) {
          int* fp = flags + ((size_t)bg * 32 + js) * 32;
          int val = gs + 1;
          asm volatile("global_store_dword %0, %1, off sc0 sc1"
                       :: "v"(fp), "v"(val) : "memory");
        }
      } else if (wv == 5) {
        const int* fp = flags + ((size_t)bg * 32 + (lane & 31)) * 32;
        const int target = gs + 1;
        int spin = 0;
        while (true) {
          int v;
          asm volatile("global_load_dword %0, %1, off sc0 sc1\n\ts_waitcnt vmcnt(0)"
                       : "=v"(v) : "v"(fp) : "memory");
          if (__all(v >= target)) break;
          __builtin_amdgcn_s_sleep(1);
          if (++spin > (1 << 18)) break;  // safety valve
        }
      }
      __syncthreads();  // (D)
      cur ^= 1;
    }
    if (g == 1) {
#pragma unroll
      for (int r = 0; r < 4; ++r)
        h32[(size_t)(b0 + lk * 4 + r) * 1024 + jcol] = hown[r];
    }
    return;
  }

  // ================= worker role =================
  const int w = blockIdx.x - 256;  // 0..255
  _Float16* As = (_Float16*)smem;
  _Float16* Bs = (_Float16*)(smem + 16384);
  float* ps = (float*)(smem + 32768);
  if (do_gin) {
    for (int tau = w; tau < 2048; tau += 256)
      gemm_in_tile(x, Wcat, bcat, rznx_n, skip_n, t0_gin, tau & 31, tau >> 5, tid,
                   As, Bs);
  }
  if (do_ln) {
    for (int row = w; row < TC * 128; row += 256)
      ln_one_row(row, hs16_p, gamma, beta, normed_p, tid, ps);
  }
  if (do_gout) {
    __syncthreads();
    gemm_out_tile(normed_pp, Wout16, bout, outp, t0_gout, w & 3, w >> 2, tid, As, Bs);
  }
}

// ---------------- host ----------------
extern "C" void kernel_launch(void* const* d_in, const int* in_sizes, int n_in,
                              void* d_out, int out_size, void* d_ws, size_t ws_size,
                              hipStream_t stream) {
  const float* x     = (const float*)d_in[0];
  const float* Wir   = (const float*)d_in[1];
  const float* bir   = (const float*)d_in[2];
  const float* Whr   = (const float*)d_in[3];
  const float* bhr   = (const float*)d_in[4];
  const float* Wiz   = (const float*)d_in[5];
  const float* biz   = (const float*)d_in[6];
  const float* Whz   = (const float*)d_in[7];
  const float* bhz   = (const float*)d_in[8];
  const float* Win   = (const float*)d_in[9];
  const float* bin_  = (const float*)d_in[10];
  const float* Whn   = (const float*)d_in[11];
  const float* bhn   = (const float*)d_in[12];
  const float* Wskip = (const float*)d_in[13];
  const float* bskip = (const float*)d_in[14];
  const float* gamma = (const float*)d_in[15];
  const float* beta  = (const float*)d_in[16];
  const float* Wout  = (const float*)d_in[17];
  const float* bout  = (const float*)d_in[18];
  float* out = (float*)d_out;

  char* ws = (char*)d_ws;
  size_t off = 0;
  auto alloc = [&](size_t bytes) -> char* {
    char* p = ws + off;
    off += (bytes + 255) & ~(size_t)255;
    return p;
  };
  // shallow region first
  _Float16* Wcat   = (_Float16*)alloc((size_t)4096 * 512 * 2);
  _Float16* Whcat  = (_Float16*)alloc((size_t)3072 * 1024 * 2);
  _Float16* Wout16 = (_Float16*)alloc((size_t)512 * 1024 * 2);
  float*    bcat   = (float*)alloc(4096 * 4);
  _Float16* h16    = (_Float16*)alloc((size_t)2 * 128 * 1024 * 2);
  float*    h32    = (float*)alloc((size_t)128 * 1024 * 4);
  int*      flags  = (int*)alloc(8 * 32 * 32 * sizeof(int));
  _Float16* rznx0  = (_Float16*)alloc((size_t)TC * 128 * 3072 * 2);
  _Float16* skip0  = (_Float16*)alloc((size_t)TC * 128 * 1024 * 2);
  _Float16* hs0    = (_Float16*)alloc((size_t)TC * 128 * 1024 * 2);
  _Float16* norm0  = (_Float16*)alloc((size_t)TC * 128 * 1024 * 2);
  size_t shallow_end = off;
  // deep-only region
  _Float16* rznx1  = (_Float16*)alloc((size_t)TC * 128 * 3072 * 2);
  _Float16* skip1  = (_Float16*)alloc((size_t)TC * 128 * 1024 * 2);
  _Float16* hs1    = (_Float16*)alloc((size_t)TC * 128 * 1024 * 2);
  _Float16* norm1  = (_Float16*)alloc((size_t)TC * 128 * 1024 * 2);
  size_t deep_end = off;
  const bool deep = ws_size >= deep_end;
  (void)shallow_end;

  _Float16* rznxA[2] = {rznx0, rznx1};
  _Float16* skipA[2] = {skip0, skip1};
  _Float16* hsA[2]   = {hs0, hs1};
  _Float16* normA[2] = {norm0, norm1};

  // prep
  k_cvt<<<512, 256, 0, stream>>>(Wir, Wcat + 0 * 524288, 131072);
  k_cvt<<<512, 256, 0, stream>>>(Wiz, Wcat + 1 * 524288, 131072);
  k_cvt<<<512, 256, 0, stream>>>(Win, Wcat + 2 * 524288, 131072);
  k_cvt<<<512, 256, 0, stream>>>(Wskip, Wcat + 3 * 524288, 131072);
  k_cvt<<<1024, 256, 0, stream>>>(Whr, Whcat + 0 * 1048576, 262144);
  k_cvt<<<1024, 256, 0, stream>>>(Whz, Whcat + 1 * 1048576, 262144);
  k_cvt<<<1024, 256, 0, stream>>>(Whn, Whcat + 2 * 1048576, 262144);
  k_cvt<<<512, 256, 0, stream>>>(Wout, Wout16, 131072);
  build_bcat<<<16, 256, 0, stream>>>(bir, biz, bin_, bskip, bcat);
  hipMemsetAsync(h16, 0, (size_t)2 * 128 * 1024 * 2, stream);
  hipMemsetAsync(h32, 0, (size_t)128 * 1024 * 4, stream);
  hipMemsetAsync(flags, 0, 8 * 32 * 32 * sizeof(int), stream);

  if (deep) {
    // prologue: input gemm chunk 0
    gemm_in_k<<<dim3(32, 64), 256, 0, stream>>>(x, Wcat, bcat, rznxA[0], skipA[0], 0);
    for (int c = 0; c < NCHUNK; ++c) {
      int gin = (c + 1 < NCHUNK) ? 1 : 0;
      int lnn = (c >= 1) ? 1 : 0;
      int got = (c >= 2) ? 1 : 0;
      fused_k<<<512, 384, 0, stream>>>(
          rznxA[c & 1], skipA[c & 1], Whcat, bhr, bhz, bhn, h16, h32, hsA[c & 1],
          flags, c,
          x, Wcat, bcat, rznxA[(c + 1) & 1], skipA[(c + 1) & 1], gin, (c + 1) * TC,
          hsA[(c - 1) & 1], gamma, beta, normA[(c - 1) & 1], lnn,
          normA[c & 1], Wout16, bout, out, got, (c - 2) * TC);
    }
    // epilogue: LN c15, gemm_out c14, c15
    ln_k<<<TC * 128, 256, 0, stream>>>(hsA[1], gamma, beta, normA[1]);
    gemm_out_k<<<dim3(4, 64), 256, 0, stream>>>(normA[0], Wout16, bout, out, 14 * TC);
    gemm_out_k<<<dim3(4, 64), 256, 0, stream>>>(normA[1], Wout16, bout, out, 15 * TC);
  } else {
    // fallback: serial R3-style pipeline, single buffers
    for (int c = 0; c < NCHUNK; ++c) {
      gemm_in_k<<<dim3(32, 64), 256, 0, stream>>>(x, Wcat, bcat, rznx0, skip0, c * TC);
      fused_k<<<256, 384, 0, stream>>>(
          rznx0, skip0, Whcat, bhr, bhz, bhn, h16, h32, hs0, flags, c,
          x, Wcat, bcat, rznx0, skip0, 0, 0,
          hs0, gamma, beta, norm0, 0,
          norm0, Wout16, bout, out, 0, 0);
      ln_k<<<TC * 128, 256, 0, stream>>>(hs0, gamma, beta, norm0);
      gemm_out_k<<<dim3(4, 64), 256, 0, stream>>>(norm0, Wout16, bout, out, c * TC);
    }
  }
}

// Round 10
// 6187.962 us; speedup vs baseline: 2.2345x; 2.2345x over previous
//
#include <hip/hip_runtime.h>

#define T_DIM 1024
#define B_DIM 128
#define I_DIM 512
#define H_DIM 1024
#define O_DIM 512
#define TC 64
#define NCHUNK (T_DIM / TC)

typedef _Float16 half8 __attribute__((ext_vector_type(8)));
typedef _Float16 half4v __attribute__((ext_vector_type(4)));
typedef float floatx4 __attribute__((ext_vector_type(4)));
typedef unsigned int uint4v __attribute__((ext_vector_type(4)));

__device__ __forceinline__ void gload_lds16(const void* g, void* l) {
  __builtin_amdgcn_global_load_lds(
      (const __attribute__((address_space(1))) void*)g,
      (__attribute__((address_space(3))) void*)l, 16, 0, 0);
}

__device__ __forceinline__ float sigmoidf_(float x) {
  return 1.f / (1.f + __expf(-x));
}
__device__ __forceinline__ float tanhf_(float x) {
  float e = __expf(fminf(-2.f * x, 60.f));
  return (1.f - e) / (1.f + e);
}

// ---------------- prep kernels ----------------
__global__ __launch_bounds__(256) void k_cvt(const float* __restrict__ s,
                                             _Float16* __restrict__ d, int n4) {
  int i = blockIdx.x * 256 + threadIdx.x;
  if (i < n4) {
    float4 v = ((const float4*)s)[i];
    half4v h = {(_Float16)v.x, (_Float16)v.y, (_Float16)v.z, (_Float16)v.w};
    ((half4v*)d)[i] = h;
  }
}

__global__ __launch_bounds__(256) void build_bcat(const float* __restrict__ a,
                                                  const float* __restrict__ b,
                                                  const float* __restrict__ c,
                                                  const float* __restrict__ d,
                                                  float* __restrict__ o) {
  int i = blockIdx.x * 256 + threadIdx.x;
  if (i < 4096) {
    const float* p = (i < 1024) ? a : (i < 2048) ? b : (i < 3072) ? c : d;
    o[i] = p[i & 1023];
  }
}

// ---------------- gemm_in: fp32 x (B,T,I) read direct; out rz[3072]+skip[1024] ----------------
__global__ __launch_bounds__(256) void gemm_in_k(
    const float* __restrict__ x, const _Float16* __restrict__ Wcat,
    const float* __restrict__ bias, _Float16* __restrict__ rz_dst,
    _Float16* __restrict__ skip_dst, int t0) {
  __shared__ __align__(16) _Float16 As[128 * 64];
  __shared__ __align__(16) _Float16 Bs[128 * 64];
  const int tid = threadIdx.x, lane = tid & 63, wv = tid >> 6;
  const int wm = wv >> 1, wn = wv & 1;
  const int lj = lane & 15, lk = lane >> 4;
  const size_t rowA0 = (size_t)blockIdx.y * 128, colB0 = (size_t)blockIdx.x * 128;
  floatx4 acc[4][4] = {};
  for (int kb = 0; kb < I_DIM; kb += 64) {
    __syncthreads();
    float4 av[8];
#pragma unroll
    for (int i = 0; i < 8; ++i) {
      int u = i * 256 + tid;
      int r = u >> 4, f4 = u & 15;
      size_t grow = rowA0 + r;
      size_t b = grow & 127, tl = grow >> 7;
      av[i] = *(const float4*)(x + (b * T_DIM + t0 + tl) * I_DIM + kb + f4 * 4);
    }
#pragma unroll
    for (int i = 0; i < 4; ++i) {
      int q = i * 256 + tid;
      int r = q >> 3, cc = q & 7;
      gload_lds16(Wcat + (colB0 + r) * (size_t)I_DIM + kb + cc * 8,
                  Bs + (size_t)(i * 4 + wv) * 512);
    }
#pragma unroll
    for (int i = 0; i < 8; ++i) {
      int u = i * 256 + tid;
      int r = u >> 4, f4 = u & 15;
      half4v h = {(_Float16)av[i].x, (_Float16)av[i].y, (_Float16)av[i].z,
                  (_Float16)av[i].w};
      *(half4v*)(As + r * 64 + f4 * 4) = h;
    }
    __syncthreads();
#pragma unroll
    for (int ks = 0; ks < 2; ++ks) {
      half8 af[4], bf[4];
#pragma unroll
      for (int am = 0; am < 4; ++am)
        af[am] = *(const half8*)(As + (wm * 64 + am * 16 + lj) * 64 + ks * 32 + lk * 8);
#pragma unroll
      for (int bn = 0; bn < 4; ++bn)
        bf[bn] = *(const half8*)(Bs + (wn * 64 + bn * 16 + lj) * 64 + ks * 32 + lk * 8);
#pragma unroll
      for (int am = 0; am < 4; ++am)
#pragma unroll
        for (int bn = 0; bn < 4; ++bn)
          acc[am][bn] =
              __builtin_amdgcn_mfma_f32_16x16x32_f16(af[am], bf[bn], acc[am][bn], 0, 0, 0);
    }
  }
#pragma unroll
  for (int am = 0; am < 4; ++am)
#pragma unroll
    for (int bn = 0; bn < 4; ++bn)
#pragma unroll
      for (int rr = 0; rr < 4; ++rr) {
        size_t grow = rowA0 + wm * 64 + am * 16 + lk * 4 + rr;
        int gcol = (int)colB0 + wn * 64 + bn * 16 + lj;
        float v = acc[am][bn][rr] + bias[gcol];
        if (gcol < 3072) rz_dst[grow * 3072 + gcol] = (_Float16)v;
        else skip_dst[grow * 1024 + (gcol - 3072)] = (_Float16)v;
      }
}

// ---------------- gemm_out: out(b,t,o) = normed @ Wout^T + bout ----------------
__global__ __launch_bounds__(256) void gemm_out_k(
    const _Float16* __restrict__ A, const _Float16* __restrict__ Bw,
    const float* __restrict__ bias, float* __restrict__ C32, int t0) {
  __shared__ __align__(16) _Float16 As[128 * 64];
  __shared__ __align__(16) _Float16 Bs[128 * 64];
  const int tid = threadIdx.x, lane = tid & 63, wv = tid >> 6;
  const int wm = wv >> 1, wn = wv & 1;
  const int lj = lane & 15, lk = lane >> 4;
  const size_t rowA0 = (size_t)blockIdx.y * 128, colB0 = (size_t)blockIdx.x * 128;
  floatx4 acc[4][4] = {};
  for (int kb = 0; kb < H_DIM; kb += 64) {
    __syncthreads();
#pragma unroll
    for (int i = 0; i < 4; ++i) {
      int q = i * 256 + tid;
      int r = q >> 3, cc = q & 7;
      gload_lds16(A + (rowA0 + r) * (size_t)H_DIM + kb + cc * 8,
                  As + (size_t)(i * 4 + wv) * 512);
    }
#pragma unroll
    for (int i = 0; i < 4; ++i) {
      int q = i * 256 + tid;
      int r = q >> 3, cc = q & 7;
      gload_lds16(Bw + (colB0 + r) * (size_t)H_DIM + kb + cc * 8,
                  Bs + (size_t)(i * 4 + wv) * 512);
    }
    __syncthreads();
#pragma unroll
    for (int ks = 0; ks < 2; ++ks) {
      half8 af[4], bf[4];
#pragma unroll
      for (int am = 0; am < 4; ++am)
        af[am] = *(const half8*)(As + (wm * 64 + am * 16 + lj) * 64 + ks * 32 + lk * 8);
#pragma unroll
      for (int bn = 0; bn < 4; ++bn)
        bf[bn] = *(const half8*)(Bs + (wn * 64 + bn * 16 + lj) * 64 + ks * 32 + lk * 8);
#pragma unroll
      for (int am = 0; am < 4; ++am)
#pragma unroll
        for (int bn = 0; bn < 4; ++bn)
          acc[am][bn] =
              __builtin_amdgcn_mfma_f32_16x16x32_f16(af[am], bf[bn], acc[am][bn], 0, 0, 0);
    }
  }
#pragma unroll
  for (int am = 0; am < 4; ++am)
#pragma unroll
    for (int bn = 0; bn < 4; ++bn)
#pragma unroll
      for (int rr = 0; rr < 4; ++rr) {
        size_t grow = rowA0 + wm * 64 + am * 16 + lk * 4 + rr;
        size_t gcol = colB0 + wn * 64 + bn * 16 + lj;
        size_t tl = grow >> 7, b = grow & 127;
        C32[b * (size_t)(T_DIM * O_DIM) + (t0 + tl) * (size_t)O_DIM + gcol] =
            acc[am][bn][rr] + bias[gcol];
      }
}

// ---------------- GRU scan over one T-chunk (R3 protocol, proven) ----------------
// grid 256 = 8 bgroups(16 rows) x 32 jslices(32 cols); block 384 = 6 waves:
// wave wv: gate g=wv%3 (0=r,1=z,2=n), j-half jh=wv/3. bg=bid&7 keeps a
// bgroup's rznx rows L2-local under round-robin dispatch. All h traffic
// sc0+sc1 (fabric-coherent, XCD-safe). z-wave writes hs16 = h + skip.
__global__ __launch_bounds__(384) void scan_kernel(
    const _Float16* __restrict__ rznx,   // [TC][128][3072]
    const _Float16* __restrict__ skip,   // [TC][128][1024]
    const _Float16* __restrict__ Whcat,  // [3][1024][1024]
    const float* __restrict__ bhr, const float* __restrict__ bhz,
    const float* __restrict__ bhn,
    _Float16* __restrict__ h16,  // [2][128][1024]
    float* __restrict__ h32,     // [128][1024]
    _Float16* __restrict__ hs16, // [TC][128][1024]  (h + skip)
    int* __restrict__ flags,     // [8][32] flags, 128B-padded
    int chunk) {
  __shared__ __align__(16) _Float16 hlds[16 * 1024];
  __shared__ float exch[2][2][16 * 17];
  __shared__ __align__(16) _Float16 hout[16][32];
  const int tid = threadIdx.x, lane = tid & 63, wv = tid >> 6;
  const int g = wv % 3, jh = wv / 3;
  const int bg = blockIdx.x & 7, js = blockIdx.x >> 3;
  const int b0 = bg * 16;
  const int jbase = js * 32 + jh * 16;
  const int lj = lane & 15, lk = lane >> 4;
  const int jcol = jbase + lj;

  half8 wf[32];
  {
    const _Float16* wb = Whcat + ((size_t)g * 1024 + jcol) * 1024 + lk * 8;
#pragma unroll
    for (int ks = 0; ks < 32; ++ks) wf[ks] = *(const half8*)(wb + ks * 32);
  }
  const float* bh = (g == 0) ? bhr : (g == 1) ? bhz : bhn;
  const float biasg = bh[jcol];
  float hown[4];
  if (g == 1) {
#pragma unroll
    for (int r = 0; r < 4; ++r) hown[r] = h32[(size_t)(b0 + lk * 4 + r) * 1024 + jcol];
  }
  int cur = 0;
  for (int t = 0; t < TC; ++t) {
    const int gs = chunk * TC + t;
    // ---- prefetch x-side gate inputs (independent of h) ----
    const _Float16* xg = rznx + ((size_t)t * 128 + b0) * 3072 + g * 1024 + jcol;
    float xv[4];
#pragma unroll
    for (int r = 0; r < 4; ++r) xv[r] = (float)xg[(size_t)(lk * 4 + r) * 3072];
    float nxv[4], skv[4];
    if (g == 1) {
#pragma unroll
      for (int r = 0; r < 4; ++r) {
        nxv[r] = (float)rznx[((size_t)t * 128 + b0 + lk * 4 + r) * 3072 + 2048 + jcol];
        skv[r] = (float)skip[((size_t)t * 128 + b0 + lk * 4 + r) * 1024 + jcol];
      }
    }
    // ---- stage h16[cur] (first 256 threads): fabric loads -> swizzled LDS ----
    if (tid < 256) {
      const _Float16* hsrc = h16 + (size_t)cur * (128 * 1024) + (size_t)b0 * 1024;
      uint4v vv[8];
      const char* ap[8];
#pragma unroll
      for (int i = 0; i < 8; ++i) {
        int q = tid + i * 256;
        int b = q >> 7, c = q & 127;
        ap[i] = (const char*)(hsrc + b * 1024 + c * 8);
      }
#pragma unroll
      for (int i = 0; i < 8; ++i)
        asm volatile("global_load_dwordx4 %0, %1, off sc0 sc1"
                     : "=v"(vv[i]) : "v"(ap[i]));
      asm volatile("s_waitcnt vmcnt(0)" ::: "memory");
#pragma unroll
      for (int i = 0; i < 8; ++i) {
        int q = tid + i * 256;
        int b = q >> 7, c = q & 127;
        *(uint4v*)((char*)hlds + b * 2048 + ((c ^ (b & 7)) * 16)) = vv[i];
      }
    }
    __syncthreads();  // (A) h staged
    floatx4 acc = {0.f, 0.f, 0.f, 0.f};
#pragma unroll
    for (int ks = 0; ks < 32; ++ks) {
      int c = ks * 4 + lk;
      int b = lj;
      half8 af = *(const half8*)((const char*)hlds + b * 2048 + ((c ^ (b & 7)) * 16));
      acc = __builtin_amdgcn_mfma_f32_16x16x32_f16(af, wf[ks], acc, 0, 0, 0);
    }
    float zv[4] = {0.f, 0.f, 0.f, 0.f};
    if (g == 0) {
#pragma unroll
      for (int r = 0; r < 4; ++r)
        exch[jh][0][(lk * 4 + r) * 17 + lj] = sigmoidf_(acc[r] + biasg + xv[r]);
    } else if (g == 2) {
#pragma unroll
      for (int r = 0; r < 4; ++r)
        exch[jh][1][(lk * 4 + r) * 17 + lj] = acc[r] + biasg;
    } else {
#pragma unroll
      for (int r = 0; r < 4; ++r) zv[r] = sigmoidf_(acc[r] + biasg + xv[r]);
    }
    __syncthreads();  // (B) exch ready
    if (g == 1) {
#pragma unroll
      for (int r = 0; r < 4; ++r) {
        float rr = exch[jh][0][(lk * 4 + r) * 17 + lj];
        float np = exch[jh][1][(lk * 4 + r) * 17 + lj];
        float n = tanhf_(nxv[r] + rr * np);
        float hn = (1.f - zv[r]) * n + zv[r] * hown[r];
        hown[r] = hn;
        hout[lk * 4 + r][jh * 16 + lj] = (_Float16)hn;
        // hs16 = h + skip (plain cached store, off critical path)
        hs16[((size_t)t * 128 + b0 + lk * 4 + r) * 1024 + jcol] = (_Float16)(hn + skv[r]);
      }
    }
    __syncthreads();  // (C) hout ready
    if (wv == 0) {
      int row = lane >> 2, c = lane & 3;
      uint4v hv = *(const uint4v*)((const char*)hout + row * 64 + c * 16);
      char* p1 = (char*)(h16 + (size_t)(cur ^ 1) * (128 * 1024) +
                         (size_t)(b0 + row) * 1024 + js * 32 + c * 8);
      asm volatile("global_store_dwordx4 %0, %1, off sc0 sc1"
                   :: "v"(p1), "v"(hv) : "memory");
      asm volatile("s_waitcnt vmcnt(0)" ::: "memory");
      if (lane == 0) {
        int* fp = flags + ((size_t)bg * 32 + js) * 32;
        int val = gs + 1;
        asm volatile("global_store_dword %0, %1, off sc0 sc1"
                     :: "v"(fp), "v"(val) : "memory");
      }
    } else if (wv == 5) {
      const int* fp = flags + ((size_t)bg * 32 + (lane & 31)) * 32;
      const int target = gs + 1;
      int spin = 0;
      while (true) {
        int v;
        asm volatile("global_load_dword %0, %1, off sc0 sc1\n\ts_waitcnt vmcnt(0)"
                     : "=v"(v) : "v"(fp) : "memory");
        if (__all(v >= target)) break;
        if (++spin > 1024) __builtin_amdgcn_s_sleep(1);  // only on slow path
        if (spin > (1 << 18)) break;  // safety valve vs hang
      }
    }
    __syncthreads();  // (D) h(gs+1) published by all blocks of bgroup
    cur ^= 1;
  }
  if (g == 1) {
#pragma unroll
    for (int r = 0; r < 4; ++r) h32[(size_t)(b0 + lk * 4 + r) * 1024 + jcol] = hown[r];
  }
}

// ---------------- LayerNorm(hs) -> fp16  (hs already = h + skip) ----------------
__global__ __launch_bounds__(256) void ln_kernel(
    const _Float16* __restrict__ hs, const float* __restrict__ gamma,
    const float* __restrict__ beta, _Float16* __restrict__ outp) {
  const int row = blockIdx.x, tid = threadIdx.x;
  const int lane = tid & 63, wv = tid >> 6;
  half4v hv = *(const half4v*)(hs + (size_t)row * 1024 + tid * 4);
  float v[4];
  float s = 0.f, s2 = 0.f;
#pragma unroll
  for (int j = 0; j < 4; ++j) {
    v[j] = (float)hv[j];
    s += v[j];
    s2 += v[j] * v[j];
  }
#pragma unroll
  for (int o = 32; o > 0; o >>= 1) {
    s += __shfl_xor(s, o, 64);
    s2 += __shfl_xor(s2, o, 64);
  }
  __shared__ float ps[4][2];
  if (lane == 0) { ps[wv][0] = s; ps[wv][1] = s2; }
  __syncthreads();
  s = ps[0][0] + ps[1][0] + ps[2][0] + ps[3][0];
  s2 = ps[0][1] + ps[1][1] + ps[2][1] + ps[3][1];
  const float mu = s * (1.f / 1024.f);
  const float var = s2 * (1.f / 1024.f) - mu * mu;
  const float rstd = rsqrtf(var + 1e-5f);
  half4v ov;
#pragma unroll
  for (int j = 0; j < 4; ++j)
    ov[j] = (_Float16)((v[j] - mu) * rstd * gamma[tid * 4 + j] + beta[tid * 4 + j]);
  *(half4v*)(outp + (size_t)row * 1024 + tid * 4) = ov;
}

// ---------------- host ----------------
extern "C" void kernel_launch(void* const* d_in, const int* in_sizes, int n_in,
                              void* d_out, int out_size, void* d_ws, size_t ws_size,
                              hipStream_t stream) {
  const float* x     = (const float*)d_in[0];
  const float* Wir   = (const float*)d_in[1];
  const float* bir   = (const float*)d_in[2];
  const float* Whr   = (const float*)d_in[3];
  const float* bhr   = (const float*)d_in[4];
  const float* Wiz   = (const float*)d_in[5];
  const float* biz   = (const float*)d_in[6];
  const float* Whz   = (const float*)d_in[7];
  const float* bhz   = (const float*)d_in[8];
  const float* Win   = (const float*)d_in[9];
  const float* bin_  = (const float*)d_in[10];
  const float* Whn   = (const float*)d_in[11];
  const float* bhn   = (const float*)d_in[12];
  const float* Wskip = (const float*)d_in[13];
  const float* bskip = (const float*)d_in[14];
  const float* gamma = (const float*)d_in[15];
  const float* beta  = (const float*)d_in[16];
  const float* Wout  = (const float*)d_in[17];
  const float* bout  = (const float*)d_in[18];
  float* out = (float*)d_out;

  char* ws = (char*)d_ws;
  size_t off = 0;
  auto alloc = [&](size_t bytes) -> char* {
    char* p = ws + off;
    off += (bytes + 255) & ~(size_t)255;
    return p;
  };
  _Float16* Wcat   = (_Float16*)alloc((size_t)4096 * 512 * 2);
  _Float16* Whcat  = (_Float16*)alloc((size_t)3072 * 1024 * 2);
  _Float16* Wout16 = (_Float16*)alloc((size_t)512 * 1024 * 2);
  float*    bcat   = (float*)alloc(4096 * 4);
  _Float16* rznx   = (_Float16*)alloc((size_t)TC * 128 * 3072 * 2);
  _Float16* skip   = (_Float16*)alloc((size_t)TC * 128 * 1024 * 2);
  _Float16* h16    = (_Float16*)alloc((size_t)2 * 128 * 1024 * 2);
  float*    h32    = (float*)alloc((size_t)128 * 1024 * 4);
  _Float16* hs16   = (_Float16*)alloc((size_t)TC * 128 * 1024 * 2);
  _Float16* normed = (_Float16*)alloc((size_t)TC * 128 * 1024 * 2);
  int*      flags  = (int*)alloc(8 * 32 * 32 * sizeof(int));

  k_cvt<<<512, 256, 0, stream>>>(Wir, Wcat + 0 * 524288, 131072);
  k_cvt<<<512, 256, 0, stream>>>(Wiz, Wcat + 1 * 524288, 131072);
  k_cvt<<<512, 256, 0, stream>>>(Win, Wcat + 2 * 524288, 131072);
  k_cvt<<<512, 256, 0, stream>>>(Wskip, Wcat + 3 * 524288, 131072);
  k_cvt<<<1024, 256, 0, stream>>>(Whr, Whcat + 0 * 1048576, 262144);
  k_cvt<<<1024, 256, 0, stream>>>(Whz, Whcat + 1 * 1048576, 262144);
  k_cvt<<<1024, 256, 0, stream>>>(Whn, Whcat + 2 * 1048576, 262144);
  k_cvt<<<512, 256, 0, stream>>>(Wout, Wout16, 131072);
  build_bcat<<<16, 256, 0, stream>>>(bir, biz, bin_, bskip, bcat);
  hipMemsetAsync(h16, 0, (size_t)2 * 128 * 1024 * 2, stream);
  hipMemsetAsync(h32, 0, (size_t)128 * 1024 * 4, stream);
  hipMemsetAsync(flags, 0, 8 * 32 * 32 * sizeof(int), stream);

  for (int c = 0; c < NCHUNK; ++c) {
    int t0 = c * TC;
    gemm_in_k<<<dim3(32, 64), 256, 0, stream>>>(x, Wcat, bcat, rznx, skip, t0);
    scan_kernel<<<256, 384, 0, stream>>>(rznx, skip, Whcat, bhr, bhz, bhn, h16, h32,
                                         hs16, flags, c);
    ln_kernel<<<TC * 128, 256, 0, stream>>>(hs16, gamma, beta, normed);
    gemm_out_k<<<dim3(4, 64), 256, 0, stream>>>(normed, Wout16, bout, out, t0);
  }
}